// Round 4
// baseline (270.434 us; speedup 1.0000x reference)
//
#include <hip/hip_runtime.h>

#define D_IN 128
#define D_H 256
#define D_OUT 128
#define N_SETS 8192
#define T_TOTAL 262144

typedef short short8 __attribute__((ext_vector_type(8)));
typedef short short4v __attribute__((ext_vector_type(4)));
typedef float floatx4 __attribute__((ext_vector_type(4)));

typedef const __attribute__((address_space(1))) unsigned int gu32;
typedef __attribute__((address_space(3))) unsigned int lu32;

__device__ inline unsigned short f32_bf16(float f) {
    unsigned int u = __float_as_uint(f);
    u += 0x7FFFu + ((u >> 16) & 1u);   // round-to-nearest-even
    return (unsigned short)(u >> 16);
}

// blocks [0,32): swizzle W1/W2 into bf16 MFMA fragment order.
// frag f -> 64 lanes x 8 bf16, lane l holds M[k = c*32 + (l>>4)*8 + j][n = nt*16 + (l&15)].
// blocks [32,1064): zero out (8192x128) and counts (8192).
__global__ void setup_kernel(const float* __restrict__ W1, const float* __restrict__ W2,
                             unsigned short* __restrict__ W1s, unsigned short* __restrict__ W2s,
                             float4* __restrict__ out4, float4* __restrict__ cnt4) {
    if (blockIdx.x < 32) {
        int t = blockIdx.x * 256 + threadIdx.x;
        int l = t & 63;
        int f = (t >> 6) & 63;
        int q = l >> 4, r = l & 15;
        if (t < 4096) {                      // W1: 16 n-tiles x 4 k-chunks
            int nt = f >> 2, c = f & 3;
            int k0 = c * 32 + q * 8, n = nt * 16 + r;
            unsigned short v[8];
#pragma unroll
            for (int j = 0; j < 8; j++) v[j] = f32_bf16(W1[(k0 + j) * D_H + n]);
#pragma unroll
            for (int j = 0; j < 8; j++) W1s[f * 512 + l * 8 + j] = v[j];
        } else {                             // W2: 8 n-tiles x 8 k-chunks
            int nt = f >> 3, c = f & 7;
            int k0 = c * 32 + q * 8, n = nt * 16 + r;
            unsigned short v[8];
#pragma unroll
            for (int j = 0; j < 8; j++) v[j] = f32_bf16(W2[(k0 + j) * D_OUT + n]);
#pragma unroll
            for (int j = 0; j < 8; j++) W2s[f * 512 + l * 8 + j] = v[j];
        }
    } else {
        int i = (blockIdx.x - 32) * 256 + threadIdx.x;
        float4 z = make_float4(0.f, 0.f, 0.f, 0.f);
        if (i < 262144) out4[i] = z;               // out: 8192*128 floats
        else if (i < 264192) cnt4[i - 262144] = z; // counts: 8192 floats
    }
}

// R4: SINGLE-VARIABLE experiment vs R3 — atomicAdd(float*) -> unsafeAtomicAdd.
// R1/R2/R3 (three different barrier/occupancy structures) all flat at ~122us
// with every pipe idle => bottleneck is invariant code. Cycle audit leaves
// ~70-90k cyc/wave unexplained; the only mechanism that big: fp32 atomicAdd
// expanded to a device-scope CAS retry loop (~64 exec-masked atomic sites/wave
// x >=2 dependent round-trips + contention). unsafeAtomicAdd emits native
// fire-and-forget global_atomic_add_f32 (coarse-grained buffers -> safe).
// Everything else is byte-identical to R3.
__global__ __launch_bounds__(768, 3) void ds_main(
    const float* __restrict__ x, const int* __restrict__ seg,
    const unsigned short* __restrict__ W1s, const float* __restrict__ b1,
    const unsigned short* __restrict__ W2s, const float* __restrict__ b2,
    float* __restrict__ out, float* __restrict__ counts)
{
    // frag f at wbuf + f*512 shorts; lane l's 16B at + l*8.
    // f in [0,64): W1 frag (nt*4 + c); f in [64,128): W2 frag (nt2*8 + kc).
    __shared__ __align__(16) unsigned short wbuf[128 * 512];     // 128 KB
    __shared__ __align__(16) unsigned short slabs[12][1280];     // per-wave 32x40 bf16; h2 overlay [16][36] f32
    __shared__ int ssegs[12][32];

    const int tid = threadIdx.x;
    const int wave = tid >> 6, lane = tid & 63;
    const int r = lane & 15, q = lane >> 4;
    const int tok0 = blockIdx.x * 384 + wave * 32;
    const bool active = (tok0 < T_TOTAL);          // wave-uniform tail guard

    // ---- one-time weight staging by waves 0..7 ----
    if (wave < 8) {
#pragma unroll
        for (int i = 0; i < 8; i++) {
            __builtin_amdgcn_global_load_lds((gu32*)(W1s + i * 4096 + tid * 8),
                                             (lu32*)(wbuf + i * 4096 + tid * 8), 16, 0, 0);
            __builtin_amdgcn_global_load_lds((gu32*)(W2s + i * 4096 + tid * 8),
                                             (lu32*)(wbuf + 32768 + i * 4096 + tid * 8), 16, 0, 0);
        }
    }

    unsigned short* slab = slabs[wave];
    int* sseg = ssegs[wave];

    // ---- x fragments direct from global (fp32 -> bf16), 2 m-tiles x 4 k-chunks ----
    short8 xfb[2][4];
    if (active) {
        if (lane < 32) sseg[lane] = seg[tok0 + lane];
#pragma unroll
        for (int mt = 0; mt < 2; mt++) {
            const float* xp = x + (size_t)(tok0 + mt * 16 + r) * D_IN + q * 8;
#pragma unroll
            for (int c = 0; c < 4; c++) {
                float4 v0 = *(const float4*)(xp + c * 32);
                float4 v1 = *(const float4*)(xp + c * 32 + 4);
                short8 w;
                w[0] = (short)f32_bf16(v0.x); w[1] = (short)f32_bf16(v0.y);
                w[2] = (short)f32_bf16(v0.z); w[3] = (short)f32_bf16(v0.w);
                w[4] = (short)f32_bf16(v1.x); w[5] = (short)f32_bf16(v1.y);
                w[6] = (short)f32_bf16(v1.z); w[7] = (short)f32_bf16(v1.w);
                xfb[mt][c] = w;
            }
        }
    }

    floatx4 acc2[8][2];
#pragma unroll
    for (int i = 0; i < 8; i++) {
        acc2[i][0] = (floatx4){0.f, 0.f, 0.f, 0.f};
        acc2[i][1] = (floatx4){0.f, 0.f, 0.f, 0.f};
    }

    __syncthreads();   // weights staged (vmcnt drained); ONLY barrier
    if (!active) return;

    // ---- fused K loop over 8 k-chunks of D_H; no barriers, all-LDS weights ----
#pragma unroll
    for (int kc = 0; kc < 8; kc++) {
        // layer 1 (transposed): produce h1 local cols [0,32) = global cols [kc*32, kc*32+32)
#pragma unroll
        for (int t = 0; t < 2; t++) {
            const int nt = kc * 2 + t;
            short8 w1f[4];
#pragma unroll
            for (int c = 0; c < 4; c++)
                w1f[c] = *(const short8*)(wbuf + (nt * 4 + c) * 512 + lane * 8);
            floatx4 b1v = *(const floatx4*)(b1 + nt * 16 + q * 4);
            floatx4 acc1[2];
            acc1[0] = (floatx4){0.f, 0.f, 0.f, 0.f};
            acc1[1] = (floatx4){0.f, 0.f, 0.f, 0.f};
#pragma unroll
            for (int c = 0; c < 4; c++) {
                acc1[0] = __builtin_amdgcn_mfma_f32_16x16x32_bf16(w1f[c], xfb[0][c], acc1[0], 0, 0, 0);
                acc1[1] = __builtin_amdgcn_mfma_f32_16x16x32_bf16(w1f[c], xfb[1][c], acc1[1], 0, 0, 0);
            }
            // D[col = nt*16 + q*4+i][tok = mt*16 + r] -> slab[tok][localcol], b64
#pragma unroll
            for (int mt = 0; mt < 2; mt++) {
                short4v pk;
#pragma unroll
                for (int i = 0; i < 4; i++)
                    pk[i] = (short)f32_bf16(fmaxf(acc1[mt][i] + b1v[i], 0.f));
                *(short4v*)(slab + (mt * 16 + r) * 40 + t * 16 + q * 4) = pk;
            }
        }
        // layer 2: A-frags from slab (in-order DS: writes above are visible)
        short8 a2[2];
        a2[0] = *(const short8*)(slab + r * 40 + q * 8);
        a2[1] = *(const short8*)(slab + (16 + r) * 40 + q * 8);
#pragma unroll
        for (int nt2 = 0; nt2 < 8; nt2++) {
            short8 bw = *(const short8*)(wbuf + (64 + nt2 * 8 + kc) * 512 + lane * 8);
            acc2[nt2][0] = __builtin_amdgcn_mfma_f32_16x16x32_bf16(a2[0], bw, acc2[nt2][0], 0, 0, 0);
            acc2[nt2][1] = __builtin_amdgcn_mfma_f32_16x16x32_bf16(a2[1], bw, acc2[nt2][1], 0, 0, 0);
        }
    }

    // ---- counts: run heads within this wave's 32 tokens ----
    if (lane < 32) {
        int s = sseg[lane];
        if (lane == 0 || sseg[lane - 1] != s) {
            int len = 1;
            for (int u = lane + 1; u < 32 && sseg[u] == s; ++u) ++len;
            unsafeAtomicAdd(&counts[s], (float)len);
        }
    }

    // ---- per-lane segment ids for its 8-token quarter (t0 = q*8) ----
    int sid[8];
#pragma unroll
    for (int e = 0; e < 8; e++) sid[e] = sseg[q * 8 + e];

    // ---- epilogue: per nt2, h2 overlay [col r][36] then run-scan + atomics ----
    float* h2 = (float*)slab;
#pragma unroll
    for (int nt2 = 0; nt2 < 8; nt2++) {
        const float bias = b2[nt2 * 16 + r];
#pragma unroll
        for (int mt = 0; mt < 2; mt++) {
            floatx4 v;
#pragma unroll
            for (int i = 0; i < 4; i++) v[i] = fmaxf(acc2[nt2][mt][i] + bias, 0.f);
            *(floatx4*)(h2 + r * 36 + mt * 16 + q * 4) = v;   // [col=r][tok=mt*16+q*4+i]
        }
        // lane (q,r): col = nt2*16 + r, tokens [q*8, q*8+8)
        floatx4 v0 = *(const floatx4*)(h2 + r * 36 + q * 8);
        floatx4 v1 = *(const floatx4*)(h2 + r * 36 + q * 8 + 4);
        const int col = nt2 * 16 + r;
        float sum = v0[0];
#pragma unroll
        for (int e = 1; e < 8; e++) {
            float v = (e < 4) ? v0[e] : v1[e - 4];
            if (sid[e] != sid[e - 1]) {
                unsafeAtomicAdd(&out[(size_t)sid[e - 1] * D_OUT + col], sum);
                sum = 0.f;
            }
            sum += v;
        }
        unsafeAtomicAdd(&out[(size_t)sid[7] * D_OUT + col], sum);
    }
}

__global__ void div_kernel(float4* __restrict__ out4, const float* __restrict__ counts) {
    int i = blockIdx.x * 256 + threadIdx.x;   // 262144 float4s, 32 per row
    float inv = 1.f / fmaxf(counts[i >> 5], 1.f);
    float4 v = out4[i];
    v.x *= inv; v.y *= inv; v.z *= inv; v.w *= inv;
    out4[i] = v;
}

extern "C" void kernel_launch(void* const* d_in, const int* in_sizes, int n_in,
                              void* d_out, int out_size, void* d_ws, size_t ws_size,
                              hipStream_t stream) {
    const float* x  = (const float*)d_in[0];
    const int* seg  = (const int*)d_in[1];
    const float* W1 = (const float*)d_in[3];
    const float* b1 = (const float*)d_in[4];
    const float* W2 = (const float*)d_in[5];
    const float* b2 = (const float*)d_in[6];
    float* out = (float*)d_out;

    float* counts       = (float*)d_ws;                                   // 32 KB
    unsigned short* W1s = (unsigned short*)((char*)d_ws + 32768);         // 64 KB
    unsigned short* W2s = (unsigned short*)((char*)d_ws + 32768 + 65536); // 64 KB

    hipLaunchKernelGGL(setup_kernel, dim3(1064), dim3(256), 0, stream,
                       W1, W2, W1s, W2s, (float4*)out, (float4*)counts);
    hipLaunchKernelGGL(ds_main, dim3(683), dim3(768), 0, stream,
                       x, seg, W1s, b1, W2s, b2, out, counts);
    hipLaunchKernelGGL(div_kernel, dim3(1024), dim3(256), 0, stream,
                       (float4*)out, counts);
}

// Round 5
// 252.354 us; speedup vs baseline: 1.0716x; 1.0716x over previous
//
#include <hip/hip_runtime.h>

#define D_IN 128
#define D_H 256
#define D_OUT 128
#define N_SETS 8192
#define T_TOTAL 262144

typedef short short8 __attribute__((ext_vector_type(8)));
typedef float floatx4 __attribute__((ext_vector_type(4)));
typedef float floatx16 __attribute__((ext_vector_type(16)));
typedef unsigned int uint4v __attribute__((ext_vector_type(4)));

typedef const __attribute__((address_space(1))) unsigned int gu32;
typedef __attribute__((address_space(3))) unsigned int lu32;

union U8 { uint4v u; short8 s; };

__device__ inline unsigned short f32_bf16(float f) {
    unsigned int u = __float_as_uint(f);
    u += 0x7FFFu + ((u >> 16) & 1u);   // round-to-nearest-even
    return (unsigned short)(u >> 16);
}

// R5 setup: swizzle W1/W2 into 32x32x16 MFMA fragment order (32 blocks only;
// zeroing moved to hipMemsetAsync). Frag = 64 lanes x 8 bf16 (16B/lane).
// W1 frag f = nt*8 + c  (nt<8 coltile, c<8 kstep):  lane l, j:
//   W1[k = c*16 + (l>>5)*8 + j][col = nt*32 + (l&31)]   (A-frag of W1^T / B-frag of W1)
// W2 frag f = 64 + o*16 + c2 (o<4, c2<16): W2[k = c2*16 + (l>>5)*8 + j][col = o*32 + (l&31)]
__global__ void setup_kernel(const float* __restrict__ W1, const float* __restrict__ W2,
                             unsigned short* __restrict__ W1s, unsigned short* __restrict__ W2s) {
    int t = blockIdx.x * 256 + threadIdx.x;
    int l = t & 63;
    int f = t >> 6;                      // 0..127
    int hl = l >> 5, c31 = l & 31;
    if (f < 64) {                        // W1: 8 col-tiles x 8 k-steps
        int nt = f >> 3, c = f & 7;
        int k0 = c * 16 + hl * 8, n = nt * 32 + c31;
        unsigned short v[8];
#pragma unroll
        for (int j = 0; j < 8; j++) v[j] = f32_bf16(W1[(k0 + j) * D_H + n]);
#pragma unroll
        for (int j = 0; j < 8; j++) W1s[f * 512 + l * 8 + j] = v[j];
    } else {                             // W2: 4 col-tiles x 16 k-steps
        int g = f - 64;
        int o = g >> 4, c2 = g & 15;
        int k0 = c2 * 16 + hl * 8, n = o * 32 + c31;
        unsigned short v[8];
#pragma unroll
        for (int j = 0; j < 8; j++) v[j] = f32_bf16(W2[(k0 + j) * D_OUT + n]);
#pragma unroll
        for (int j = 0; j < 8; j++) W2s[g * 512 + l * 8 + j] = v[j];
    }
}

// R5: in-register layer handoff via 32x32x16 MFMA + permlane32_swap.
// R1-R4: four structures (barriers, occupancy, atomics varied) all ~122us ->
// the invariant per-wave dataflow (slab LDS round-trip each kc + epilogue LDS
// round-trip + 240 DS ops + 256 MFMAs) is the suspect serial chain.
// Now: D1 = W1^T x^T (32x32x16): lane holds tok=l&31, 16 h1-cols; lanes l,l+32
// share tok with complementary col-sets -> 8 cvt_pk + 4 permlane32_swap build
// layer-2 A-frags IN REGISTERS (no slab). Layer 2: D2 = h W2: lane holds
// outcol=l&31, 16 toks; 8 permlane swaps make toks contiguous -> run-scan +
// atomics straight from regs (no LDS overlay). Per wave: 128 MFMA, 128 b128
// weight reads (linear, conflict-free), zero DS round-trips. Weights fully
// LDS-resident (128KB), 12 waves/block, one barrier.
__global__ __launch_bounds__(768, 3) void ds_main(
    const float* __restrict__ x, const int* __restrict__ seg,
    const unsigned short* __restrict__ W1s, const float* __restrict__ b1,
    const unsigned short* __restrict__ W2s, const float* __restrict__ b2,
    float* __restrict__ out, float* __restrict__ counts)
{
    __shared__ __align__(16) unsigned short wbuf[128 * 512];     // 128 KB: frags 0..63 W1, 64..127 W2
    __shared__ int ssegs[12][32];

    const int tid = threadIdx.x;
    const int wave = tid >> 6, lane = tid & 63;
    const int hl = lane >> 5, c31 = lane & 31;
    const int tok0 = blockIdx.x * 384 + wave * 32;
    const bool active = (tok0 < T_TOTAL);          // wave-uniform tail guard

    // ---- one-time weight staging by waves 0..7 (16B/lane, linear) ----
    if (wave < 8) {
#pragma unroll
        for (int i = 0; i < 8; i++) {
            __builtin_amdgcn_global_load_lds((gu32*)(W1s + i * 4096 + tid * 8),
                                             (lu32*)(wbuf + i * 4096 + tid * 8), 16, 0, 0);
            __builtin_amdgcn_global_load_lds((gu32*)(W2s + i * 4096 + tid * 8),
                                             (lu32*)(wbuf + 32768 + i * 4096 + tid * 8), 16, 0, 0);
        }
    }

    int* sseg = ssegs[wave];

    // ---- x fragments (fp32 -> bf16 via cvt_pk): lane = tok c31, k = c*16 + hl*8 + j ----
    short8 xfa[8];
    if (active) {
        if (lane < 32) sseg[lane] = seg[tok0 + lane];
        const float* xp = x + (size_t)(tok0 + c31) * D_IN + hl * 8;
#pragma unroll
        for (int c = 0; c < 8; c++) {
            float4 v0 = *(const float4*)(xp + c * 16);
            float4 v1 = *(const float4*)(xp + c * 16 + 4);
            unsigned int p0, p1, p2, p3;
            asm("v_cvt_pk_bf16_f32 %0, %1, %2" : "=v"(p0) : "v"(v0.x), "v"(v0.y));
            asm("v_cvt_pk_bf16_f32 %0, %1, %2" : "=v"(p1) : "v"(v0.z), "v"(v0.w));
            asm("v_cvt_pk_bf16_f32 %0, %1, %2" : "=v"(p2) : "v"(v1.x), "v"(v1.y));
            asm("v_cvt_pk_bf16_f32 %0, %1, %2" : "=v"(p3) : "v"(v1.z), "v"(v1.w));
            U8 u; u.u = (uint4v){p0, p1, p2, p3};
            xfa[c] = u.s;
        }
    }

    floatx16 acc2[4];
#pragma unroll
    for (int o = 0; o < 4; o++)
#pragma unroll
        for (int i = 0; i < 16; i++) acc2[o][i] = 0.f;

    __syncthreads();   // weights staged; ONLY barrier
    if (!active) return;

    // ---- fused pipeline over 8 h1 col-tiles (32 cols each) ----
#pragma unroll
    for (int nt = 0; nt < 8; nt++) {
        // layer 1: acc1 = W1^T-tile x x^T  (D: col=lane&31=tok, row=h1col pattern)
        floatx16 acc1;
#pragma unroll
        for (int i = 0; i < 16; i++) acc1[i] = 0.f;
#pragma unroll
        for (int c = 0; c < 8; c++) {
            short8 wf = *(const short8*)(wbuf + (nt * 8 + c) * 512 + lane * 8);
            acc1 = __builtin_amdgcn_mfma_f32_32x32x16_bf16(wf, xfa[c], acc1, 0, 0, 0);
        }
        // bias + relu: reg r -> h1col = nt*32 + (r&3) + 8*(r>>2) + 4*hl
        float v[16];
#pragma unroll
        for (int g = 0; g < 4; g++) {
            floatx4 bv = *(const floatx4*)(b1 + nt * 32 + g * 8 + hl * 4);
#pragma unroll
            for (int i = 0; i < 4; i++) v[g * 4 + i] = fmaxf(acc1[g * 4 + i] + bv[i], 0.f);
        }
        // pack pairs: pk[p] = bf16(v[2p]) | bf16(v[2p+1])<<16  (cols 8*(p>>1)+2*(p&1)+{0,1}+4hl)
        unsigned int pk[8];
#pragma unroll
        for (int p = 0; p < 8; p++)
            asm("v_cvt_pk_bf16_f32 %0, %1, %2" : "=v"(pk[p]) : "v"(v[2 * p]), "v"(v[2 * p + 1]));
        // assemble layer-2 A-frags (k = c2*16 + hl*8 + {0..7}) via permlane32_swap, then MFMA
#pragma unroll
        for (int s = 0; s < 2; s++) {
            unsigned int d0 = pk[s * 4 + 0], d2 = pk[s * 4 + 2];
            asm("v_permlane32_swap_b32 %0, %1" : "+v"(d0), "+v"(d2));
            unsigned int d1 = pk[s * 4 + 1], d3 = pk[s * 4 + 3];
            asm("v_permlane32_swap_b32 %0, %1" : "+v"(d1), "+v"(d3));
            U8 u; u.u = (uint4v){d0, d1, d2, d3};
            const short8 hf = u.s;
            const int c2 = nt * 2 + s;
#pragma unroll
            for (int o = 0; o < 4; o++) {
                short8 bw = *(const short8*)(wbuf + (64 + o * 16 + c2) * 512 + lane * 8);
                acc2[o] = __builtin_amdgcn_mfma_f32_32x32x16_bf16(hf, bw, acc2[o], 0, 0, 0);
            }
        }
    }

    // ---- counts: run heads within this wave's 32 tokens ----
    if (lane < 32) {
        int s = sseg[lane];
        if (lane == 0 || sseg[lane - 1] != s) {
            int len = 1;
            for (int u = lane + 1; u < 32 && sseg[u] == s; ++u) ++len;
            atomicAdd(&counts[s], (float)len);
        }
    }

    // ---- epilogue: lane owns outcol per o-tile; swaps -> contiguous 16 toks; run-scan ----
    int sid[16];
#pragma unroll
    for (int e = 0; e < 16; e++) sid[e] = sseg[hl * 16 + e];

#pragma unroll
    for (int o = 0; o < 4; o++) {
        const float bias = b2[o * 32 + c31];
        float val[16];
#pragma unroll
        for (int r = 0; r < 16; r++) val[r] = fmaxf(acc2[o][r] + bias, 0.f);
        // regs -> token order: lo-lanes toks 0..15, hi-lanes 16..31
        float st[16];
#pragma unroll
        for (int i = 0; i < 4; i++) {
            float a = val[i], b = val[8 + i];
            asm("v_permlane32_swap_b32 %0, %1" : "+v"(a), "+v"(b));
            st[i] = a; st[4 + i] = b;
            float c = val[4 + i], d = val[12 + i];
            asm("v_permlane32_swap_b32 %0, %1" : "+v"(c), "+v"(d));
            st[8 + i] = c; st[12 + i] = d;
        }
        const int col = o * 32 + c31;
        float sum = st[0];
#pragma unroll
        for (int e = 1; e < 16; e++) {
            if (sid[e] != sid[e - 1]) {
                atomicAdd(&out[(size_t)sid[e - 1] * D_OUT + col], sum);
                sum = 0.f;
            }
            sum += st[e];
        }
        atomicAdd(&out[(size_t)sid[15] * D_OUT + col], sum);
    }
}

__global__ void div_kernel(float4* __restrict__ out4, const float* __restrict__ counts) {
    int i = blockIdx.x * 256 + threadIdx.x;   // 262144 float4s, 32 per row
    float inv = 1.f / fmaxf(counts[i >> 5], 1.f);
    float4 v = out4[i];
    v.x *= inv; v.y *= inv; v.z *= inv; v.w *= inv;
    out4[i] = v;
}

extern "C" void kernel_launch(void* const* d_in, const int* in_sizes, int n_in,
                              void* d_out, int out_size, void* d_ws, size_t ws_size,
                              hipStream_t stream) {
    const float* x  = (const float*)d_in[0];
    const int* seg  = (const int*)d_in[1];
    const float* W1 = (const float*)d_in[3];
    const float* b1 = (const float*)d_in[4];
    const float* W2 = (const float*)d_in[5];
    const float* b2 = (const float*)d_in[6];
    float* out = (float*)d_out;

    float* counts       = (float*)d_ws;                                   // 32 KB
    unsigned short* W1s = (unsigned short*)((char*)d_ws + 32768);         // 64 KB
    unsigned short* W2s = (unsigned short*)((char*)d_ws + 32768 + 65536); // 64 KB

    hipMemsetAsync(out, 0, (size_t)N_SETS * D_OUT * sizeof(float), stream);
    hipMemsetAsync(counts, 0, (size_t)N_SETS * sizeof(float), stream);
    hipLaunchKernelGGL(setup_kernel, dim3(32), dim3(256), 0, stream,
                       W1, W2, W1s, W2s);
    hipLaunchKernelGGL(ds_main, dim3(683), dim3(768), 0, stream,
                       x, seg, W1s, b1, W2s, b2, out, counts);
    hipLaunchKernelGGL(div_kernel, dim3(1024), dim3(256), 0, stream,
                       (float4*)out, counts);
}